// Round 10
// baseline (472.120 us; speedup 1.0000x reference)
//
#include <hip/hip_runtime.h>

// MultiHeadAttention: B=4, T=2048, C=1024, H=16, HD=64
// prep WtQ/K/V -> fused QKV GEMM -> flash attention -> prep WtO -> out GEMM.
// This round: BK=64 (16 K-steps, half the barriers, 2x compute per interval)
// in both GEMMs; round-6 grid mapping restored (r9 XCD swizzle reverted:
// it cut FETCH 176->82MB but cost 20us); attn MFMA wrapped in s_setprio (T5).
// B-operand LDS swizzle for 64-col rows: phys granule = g ^ (row&7), applied
// on gld_lds SOURCE col and on ds_read addr (both-sides involution).
// Workspace (64 MiB): R0 Kp | R1 Qp->WtO | R2 Vc | R3 WtQ/K/V -> Y

#define BATCH 4
#define T_SEQ 2048
#define C_DIM 1024
#define NH 16
#define HD 64

typedef _Float16 f16;
typedef __attribute__((ext_vector_type(4))) _Float16 half4;
typedef __attribute__((ext_vector_type(8))) _Float16 half8;
typedef __attribute__((ext_vector_type(4))) float f32x4;

__device__ inline void gld_lds16(const f16* g, f16* l) {
    __builtin_amdgcn_global_load_lds(
        (const __attribute__((address_space(1))) void*)g,
        (__attribute__((address_space(3))) void*)l, 16, 0, 0);
}

// ---------------------------------------------------------------------------
// prep: dst[n][k] f16 = (f32 src[k][n]) transposed. 64x64 tile per block.
// ---------------------------------------------------------------------------
__device__ inline void prep_tile(const float* __restrict__ src, f16* __restrict__ dst)
{
    __shared__ __align__(16) f16 Tl[64][72];
    const int tid = threadIdx.x;
    const int k0 = blockIdx.x * 64, n0 = blockIdx.y * 64;
#pragma unroll
    for (int p = 0; p < 4; ++p) {
        const int kr = p * 16 + (tid >> 4);
        const int nc = (tid & 15) * 4;
        float4 v = *(const float4*)(src + (size_t)(k0 + kr) * C_DIM + n0 + nc);
        Tl[nc + 0][kr] = (f16)v.x;
        Tl[nc + 1][kr] = (f16)v.y;
        Tl[nc + 2][kr] = (f16)v.z;
        Tl[nc + 3][kr] = (f16)v.w;
    }
    __syncthreads();
#pragma unroll
    for (int p = 0; p < 2; ++p) {
        const int nr = p * 32 + (tid >> 3);
        const int kc = (tid & 7) * 8;
        *(half8*)(dst + (size_t)(n0 + nr) * C_DIM + k0 + kc) = *(const half8*)&Tl[nr][kc];
    }
}

__global__ __launch_bounds__(256) void prep_weights(const float* __restrict__ src,
                                                    f16* __restrict__ dst)
{
    prep_tile(src, dst);
}

__global__ __launch_bounds__(256) void prep_weights3(const float* __restrict__ W0,
                                                     const float* __restrict__ W1,
                                                     const float* __restrict__ W2,
                                                     f16* __restrict__ D0,
                                                     f16* __restrict__ D1,
                                                     f16* __restrict__ D2)
{
    const int z = blockIdx.z;
    const float* src = (z == 0) ? W0 : (z == 1) ? W1 : W2;
    f16* dst = (z == 0) ? D0 : (z == 1) ? D1 : D2;
    prep_tile(src, dst);
}

// ---------------------------------------------------------------------------
// Fused QKV projection GEMM: 3 x (8192x1024 = X @ W + b). Grid (192,8).
// g = blockIdx.x>>6 picks {X, Wt, bias, output layout}.
// 128x128 tile, 4 waves, 4x4 MFMA, BK=64, 16 K-steps, 2-phase dbuf:
// prefetch A(kt+1)->regs (8 float4) + B(kt+1) gld_lds (4/thread) into buf^1,
// 32 MFMA on buf, cvt+ds_write A, ONE __syncthreads per K-step.
// A LDS: [128][72] f16 (stride-72, conflict-free). B LDS: [128][64] f16 with
// granule swizzle phys = g ^ (row&7) (source col permuted, read addr XORed).
// g=0: f16 head-major Q, scaled 0.125*log2e.
// g=1: f16 head-major K, d-granule rotation ((d>>3)+t)&7.
// g=2: f16 chunked V [head][t>>6][d][key], key-granule rotation ((t>>3)+d)&7.
// ---------------------------------------------------------------------------
__global__ __launch_bounds__(256) void qkv_gemm(const float* __restrict__ Xq,
                                                const float* __restrict__ Xk,
                                                const float* __restrict__ Xv,
                                                const f16* __restrict__ Wt3,
                                                const float* __restrict__ bqp,
                                                const float* __restrict__ bkp,
                                                const float* __restrict__ bvp,
                                                f16* __restrict__ Qp,
                                                f16* __restrict__ Kp,
                                                f16* __restrict__ Vc)
{
    __shared__ __align__(16) f16 As[2][128 * 72];
    __shared__ __align__(16) f16 Bs[2][128 * 64];

    const int g = blockIdx.x >> 6;
    const float* __restrict__ Xf   = (g == 0) ? Xq : (g == 1) ? Xk : Xv;
    const float* __restrict__ bias = (g == 0) ? bqp : (g == 1) ? bkp : bvp;
    const f16* __restrict__ Wt     = Wt3 + (size_t)g * C_DIM * C_DIM;
    f16* __restrict__ outH         = (g == 0) ? Qp : (g == 1) ? Kp : Vc;

    const int tid  = threadIdx.x;
    const int m0   = (blockIdx.x & 63) * 128;
    const int n0   = blockIdx.y * 128;
    const int lane = tid & 63;
    const int wv   = tid >> 6;
    const int wm   = (wv >> 1) * 64;
    const int wn   = (wv & 1) * 64;
    const int l15  = lane & 15;
    const int quad = lane >> 4;
    // A staging: thread covers row ar, 32 cols at ach
    const int ar   = tid >> 1;
    const int ach  = (tid & 1) * 32;
    // B staging: wave wv covers segments wv*4..wv*4+3 (8 rows x 64 f16 each)
    const int br8  = lane >> 3;                               // row within segment
    const int bg   = ((lane & 7) ^ ((lane >> 3) & 7)) << 3;   // swizzled source col

    f32x4 acc[4][4];
#pragma unroll
    for (int i = 0; i < 4; i++)
#pragma unroll
        for (int j = 0; j < 4; j++) acc[i][j] = (f32x4){0.f, 0.f, 0.f, 0.f};

    float4 av[8];

    // ---- prologue: stage tile 0 into buf 0 ----
#pragma unroll
    for (int j = 0; j < 8; j++)
        av[j] = *(const float4*)(Xf + (size_t)(m0 + ar) * C_DIM + ach + j * 4);
#pragma unroll
    for (int j = 0; j < 4; j++) {
        half8 h;
        h[0] = (f16)av[2 * j].x;     h[1] = (f16)av[2 * j].y;
        h[2] = (f16)av[2 * j].z;     h[3] = (f16)av[2 * j].w;
        h[4] = (f16)av[2 * j + 1].x; h[5] = (f16)av[2 * j + 1].y;
        h[6] = (f16)av[2 * j + 1].z; h[7] = (f16)av[2 * j + 1].w;
        *(half8*)&As[0][ar * 72 + ach + j * 8] = h;
    }
#pragma unroll
    for (int i = 0; i < 4; ++i)
        gld_lds16(Wt + (size_t)(n0 + (wv * 4 + i) * 8 + br8) * C_DIM + bg,
                  &Bs[0][(wv * 4 + i) * 512]);
    __syncthreads();

    for (int kt = 0; kt < 16; ++kt) {
        const int cur = kt & 1, nxt = cur ^ 1;
        const int kk  = (kt + 1) * 64;

        // ---- prefetch tile kt+1 ----
        if (kt < 15) {
#pragma unroll
            for (int j = 0; j < 8; j++)
                av[j] = *(const float4*)(Xf + (size_t)(m0 + ar) * C_DIM + kk + ach + j * 4);
#pragma unroll
            for (int i = 0; i < 4; ++i)
                gld_lds16(Wt + (size_t)(n0 + (wv * 4 + i) * 8 + br8) * C_DIM + kk + bg,
                          &Bs[nxt][(wv * 4 + i) * 512]);
        }

        // ---- compute on buf cur: 2 K-halves x 16 MFMA ----
        half8 af[4][2], bf[4][2];
#pragma unroll
        for (int t = 0; t < 4; t++)
#pragma unroll
            for (int kh = 0; kh < 2; kh++) {
                af[t][kh] = *(const half8*)&As[cur][(wm + t * 16 + l15) * 72 + kh * 32 + quad * 8];
                bf[t][kh] = *(const half8*)&Bs[cur][(wn + t * 16 + l15) * 64 +
                                                    (((kh * 4 + quad) ^ (l15 & 7)) << 3)];
            }
#pragma unroll
        for (int kh = 0; kh < 2; kh++)
#pragma unroll
            for (int tm = 0; tm < 4; tm++)
#pragma unroll
                for (int tn = 0; tn < 4; tn++)
                    acc[tm][tn] = __builtin_amdgcn_mfma_f32_16x16x32_f16(af[tm][kh], bf[tn][kh], acc[tm][tn], 0, 0, 0);

        // ---- write prefetched A into As[nxt] ----
        if (kt < 15) {
#pragma unroll
            for (int j = 0; j < 4; j++) {
                half8 h;
                h[0] = (f16)av[2 * j].x;     h[1] = (f16)av[2 * j].y;
                h[2] = (f16)av[2 * j].z;     h[3] = (f16)av[2 * j].w;
                h[4] = (f16)av[2 * j + 1].x; h[5] = (f16)av[2 * j + 1].y;
                h[6] = (f16)av[2 * j + 1].z; h[7] = (f16)av[2 * j + 1].w;
                *(half8*)&As[nxt][ar * 72 + ach + j * 8] = h;
            }
        }
        __syncthreads();
    }

    // ---- epilogue (g is wave-uniform) ----
#pragma unroll
    for (int tm = 0; tm < 4; tm++) {
        const int gmb = m0 + wm + tm * 16 + quad * 4;
#pragma unroll
        for (int tn = 0; tn < 4; tn++) {
            const int gn = n0 + wn + tn * 16 + l15;
            const float bv = bias[gn];
            const int h = gn >> 6;
            const int d = gn & 63;
#pragma unroll
            for (int r = 0; r < 4; r++) {
                const int row = gmb + r;
                const float val = acc[tm][tn][r] + bv;
                const int b = row >> 11;
                const int t = row & (T_SEQ - 1);
                const size_t hb = ((size_t)(b * NH + h)) * T_SEQ * HD;
                if (g == 0) {
                    outH[hb + (size_t)t * HD + d] = (f16)(val * 0.18033688f); // 0.125*log2e
                } else if (g == 1) {
                    outH[hb + (size_t)t * HD + ((((d >> 3) + t) & 7) << 3) + (d & 7)] = (f16)val;
                } else {
                    outH[hb + (size_t)(t >> 6) * 4096 + d * 64 +
                         ((((t >> 3) + d) & 7) << 3) + (t & 7)] = (f16)val;
                }
            }
        }
    }
}

// ---------------------------------------------------------------------------
// Out GEMM: out(8192x1024) f32 = Y(f16) @ WtO + bo. Grid (64,8). BK=64,
// both operands gld_lds into [128][64] with granule swizzle, 2-phase dbuf.
// ---------------------------------------------------------------------------
__global__ __launch_bounds__(256) void gemm_out(const f16* __restrict__ Xh,
                                                const f16* __restrict__ Wt,
                                                const float* __restrict__ bias,
                                                float* __restrict__ outF)
{
    __shared__ __align__(16) f16 As[2][128 * 64];
    __shared__ __align__(16) f16 Bs[2][128 * 64];

    const int tid  = threadIdx.x;
    const int m0   = blockIdx.x * 128;
    const int n0   = blockIdx.y * 128;
    const int lane = tid & 63;
    const int wv   = tid >> 6;
    const int wm   = (wv >> 1) * 64;
    const int wn   = (wv & 1) * 64;
    const int l15  = lane & 15;
    const int quad = lane >> 4;
    const int br8  = lane >> 3;
    const int bg   = ((lane & 7) ^ ((lane >> 3) & 7)) << 3;

    f32x4 acc[4][4];
#pragma unroll
    for (int i = 0; i < 4; i++)
#pragma unroll
        for (int j = 0; j < 4; j++) acc[i][j] = (f32x4){0.f, 0.f, 0.f, 0.f};

    // ---- prologue: stage tile 0 ----
#pragma unroll
    for (int i = 0; i < 4; ++i) {
        gld_lds16(Xh + (size_t)(m0 + (wv * 4 + i) * 8 + br8) * C_DIM + bg, &As[0][(wv * 4 + i) * 512]);
        gld_lds16(Wt + (size_t)(n0 + (wv * 4 + i) * 8 + br8) * C_DIM + bg, &Bs[0][(wv * 4 + i) * 512]);
    }
    __syncthreads();

    for (int kt = 0; kt < 16; ++kt) {
        const int cur = kt & 1, nxt = cur ^ 1;
        const int kk  = (kt + 1) * 64;

        if (kt < 15) {
#pragma unroll
            for (int i = 0; i < 4; ++i) {
                gld_lds16(Xh + (size_t)(m0 + (wv * 4 + i) * 8 + br8) * C_DIM + kk + bg, &As[nxt][(wv * 4 + i) * 512]);
                gld_lds16(Wt + (size_t)(n0 + (wv * 4 + i) * 8 + br8) * C_DIM + kk + bg, &Bs[nxt][(wv * 4 + i) * 512]);
            }
        }

        half8 af[4][2], bf[4][2];
#pragma unroll
        for (int t = 0; t < 4; t++)
#pragma unroll
            for (int kh = 0; kh < 2; kh++) {
                const int xs = ((kh * 4 + quad) ^ (l15 & 7)) << 3;
                af[t][kh] = *(const half8*)&As[cur][(wm + t * 16 + l15) * 64 + xs];
                bf[t][kh] = *(const half8*)&Bs[cur][(wn + t * 16 + l15) * 64 + xs];
            }
#pragma unroll
        for (int kh = 0; kh < 2; kh++)
#pragma unroll
            for (int tm = 0; tm < 4; tm++)
#pragma unroll
                for (int tn = 0; tn < 4; tn++)
                    acc[tm][tn] = __builtin_amdgcn_mfma_f32_16x16x32_f16(af[tm][kh], bf[tn][kh], acc[tm][tn], 0, 0, 0);
        __syncthreads();
    }

#pragma unroll
    for (int tm = 0; tm < 4; tm++) {
        const int gmb = m0 + wm + tm * 16 + quad * 4;
#pragma unroll
        for (int tn = 0; tn < 4; tn++) {
            const int gn = n0 + wn + tn * 16 + l15;
            const float bv = bias[gn];
#pragma unroll
            for (int r = 0; r < 4; r++)
                outF[(size_t)(gmb + r) * C_DIM + gn] = acc[tm][tn][r] + bv;
        }
    }
}

// ---------------------------------------------------------------------------
// Flash attention — round-6 version (XCD-local bh remap) + T5 setprio around
// the MFMA clusters.
// ---------------------------------------------------------------------------
__global__ __launch_bounds__(256) void attn_kernel(const f16* __restrict__ Qp,
                                                   const f16* __restrict__ Kp,
                                                   const f16* __restrict__ Vc,
                                                   f16* __restrict__ Y)
{
    __shared__ __align__(16) f16 Ks[2][4096];
    __shared__ __align__(16) f16 Vs[2][4096];

    const int tid  = threadIdx.x;
    const int lane = tid & 63;
    const int wv   = tid >> 6;
    const int l15  = lane & 15;
    const int quad = lane >> 4;
    const int bh   = blockIdx.x & 63;   // same-bh blocks -> same XCD
    const int ub   = blockIdx.x >> 6;
    const int u    = (ub << 2) | wv;   // 0..63
    int qT[2];
    qT[0] = 16 * u;
    qT[1] = 2032 - 16 * u;

    const f16* Qh = Qp + (size_t)bh * T_SEQ * HD;
    const f16* Kh = Kp + (size_t)bh * T_SEQ * HD;
    const f16* Vh = Vc + (size_t)bh * T_SEQ * HD;

    half8 aq[2][2];
#pragma unroll
    for (int m = 0; m < 2; m++)
#pragma unroll
        for (int kh = 0; kh < 2; kh++)
            aq[m][kh] = *(const half8*)(Qh + (size_t)(qT[m] + l15) * HD + kh * 32 + quad * 8);

    f32x4 o[2][4];
#pragma unroll
    for (int m = 0; m < 2; m++)
#pragma unroll
        for (int dt = 0; dt < 4; dt++) o[m][dt] = (f32x4){0.f, 0.f, 0.f, 0.f};
    float lsum[2] = {0.f, 0.f};

    const int nC0   = (16 * u + 79) >> 6;
    const int nC1   = (2111 - 16 * u) >> 6;
    const int nCblk = (2111 - 64 * ub) >> 6;

    auto stage = [&](int buf, int kc) {
        const f16* kg = Kh + (size_t)kc * 4096 + wv * 512;
        const f16* vg = Vh + (size_t)kc * 4096 + wv * 512;
        f16* kl = &Ks[buf][wv * 512];
        f16* vl = &Vs[buf][wv * 512];
        gld_lds16(kg + lane * 8, kl);
        gld_lds16(kg + 2048 + lane * 8, kl + 2048);
        gld_lds16(vg + lane * 8, vl);
        gld_lds16(vg + 2048 + lane * 8, vl + 2048);
    };

    stage(0, 0);
    __syncthreads();

    for (int kc = 0; kc < nCblk; ++kc) {
        const int cur = kc & 1;
        if (kc + 1 < nCblk) stage(cur ^ 1, kc + 1);

        if (kc < nC1) {
            const int k0 = kc * 64;
            const int mStart = (kc < nC0) ? 0 : 1;

            f32x4 st[2][4];
            __builtin_amdgcn_s_setprio(1);
#pragma unroll
            for (int nt = 0; nt < 4; ++nt) {
                const f16* kr = &Ks[cur][(nt * 16 + l15) * 64];
                half8 bk0 = *(const half8*)(kr + (((quad + l15) & 7) << 3));
                half8 bk1 = *(const half8*)(kr + (((4 + quad + l15) & 7) << 3));
                {
                    f32x4 z = (f32x4){0.f, 0.f, 0.f, 0.f};
                    z = __builtin_amdgcn_mfma_f32_16x16x32_f16(bk0, aq[1][0], z, 0, 0, 0);
                    z = __builtin_amdgcn_mfma_f32_16x16x32_f16(bk1, aq[1][1], z, 0, 0, 0);
                    st[1][nt] = z;
                }
                if (mStart == 0) {
                    f32x4 z = (f32x4){0.f, 0.f, 0.f, 0.f};
                    z = __builtin_amdgcn_mfma_f32_16x16x32_f16(bk0, aq[0][0], z, 0, 0, 0);
                    z = __builtin_amdgcn_mfma_f32_16x16x32_f16(bk1, aq[0][1], z, 0, 0, 0);
                    st[0][nt] = z;
                }
            }
            __builtin_amdgcn_s_setprio(0);

            half4 pf[2][4];
#pragma unroll
            for (int m = 0; m < 2; ++m) {
                if (m < mStart) continue;
                const bool needMask = (k0 + 63 > qT[m]);
                const int q = qT[m] + l15;
#pragma unroll
                for (int nt = 0; nt < 4; ++nt) {
#pragma unroll
                    for (int r = 0; r < 4; ++r) {
                        const int key = k0 + nt * 16 + quad * 4 + r;
                        float p = __builtin_exp2f(st[m][nt][r]);
                        if (needMask && key > q) p = 0.f;
                        lsum[m] += p;
                        pf[m][nt][r] = (f16)p;
                    }
                }
            }

            __builtin_amdgcn_s_setprio(1);
#pragma unroll
            for (int nt = 0; nt < 4; ++nt) {
                const int c0 = nt * 2 + (quad >> 1);
#pragma unroll
                for (int dt = 0; dt < 4; ++dt) {
                    const int d = dt * 16 + l15;
                    half4 bv = *(const half4*)(&Vs[cur][d * 64 + (((c0 + d) & 7) << 3) + ((quad & 1) << 2)]);
                    o[1][dt] = __builtin_amdgcn_mfma_f32_16x16x16f16(pf[1][nt], bv, o[1][dt], 0, 0, 0);
                    if (mStart == 0)
                        o[0][dt] = __builtin_amdgcn_mfma_f32_16x16x16f16(pf[0][nt], bv, o[0][dt], 0, 0, 0);
                }
            }
            __builtin_amdgcn_s_setprio(0);
        }
        __syncthreads();
    }

    const int b = bh >> 4;
    const int h = bh & 15;
#pragma unroll
    for (int m = 0; m < 2; m++) {
        float l = lsum[m];
        l += __shfl_xor(l, 16);
        l += __shfl_xor(l, 32);
#pragma unroll
        for (int r = 0; r < 4; r++) {
            const float lr  = __shfl(l, quad * 4 + r);
            const float inv = 1.0f / lr;
            const int qr = qT[m] + quad * 4 + r;
#pragma unroll
            for (int dt = 0; dt < 4; dt++)
                Y[((size_t)(b * T_SEQ + qr)) * C_DIM + h * HD + dt * 16 + l15] = (f16)(o[m][dt][r] * inv);
        }
    }
}

// ---------------------------------------------------------------------------
extern "C" void kernel_launch(void* const* d_in, const int* in_sizes, int n_in,
                              void* d_out, int out_size, void* d_ws, size_t ws_size,
                              hipStream_t stream)
{
    const float* k  = (const float*)d_in[0];
    const float* q  = (const float*)d_in[1];
    const float* v  = (const float*)d_in[2];
    const float* Wk = (const float*)d_in[4];
    const float* bk = (const float*)d_in[5];
    const float* Wq = (const float*)d_in[6];
    const float* bq = (const float*)d_in[7];
    const float* Wv = (const float*)d_in[8];
    const float* bv = (const float*)d_in[9];
    const float* Wo = (const float*)d_in[10];
    const float* bo = (const float*)d_in[11];
    float* out = (float*)d_out;

    const size_t E  = (size_t)BATCH * T_SEQ * C_DIM;
    const size_t WE = (size_t)C_DIM * C_DIM;

    f16* R0 = (f16*)d_ws;
    f16* R1 = R0 + E;
    f16* R2 = R1 + E;
    f16* R3 = R2 + E;

    f16* Kp  = R0;
    f16* Qp  = R1;
    f16* Vc  = R2;
    f16* Y   = R3;
    f16* WtQ = R3;
    f16* WtK = R3 + WE;
    f16* WtV = R3 + 2 * WE;
    f16* WtO = R1;

    dim3 blk(256);
    prep_weights3<<<dim3(16, 16, 3), blk, 0, stream>>>(Wq, Wk, Wv, WtQ, WtK, WtV);
    qkv_gemm<<<dim3(192, 8), blk, 0, stream>>>(q, k, v, WtQ, bq, bk, bv, Qp, Kp, Vc);
    attn_kernel<<<dim3(1024), blk, 0, stream>>>(Qp, Kp, Vc, Y);
    prep_weights<<<dim3(16, 16), blk, 0, stream>>>(Wo, WtO);
    gemm_out<<<dim3(64, 8), blk, 0, stream>>>(Y, WtO, bo, out);
}

// Round 11
// 419.963 us; speedup vs baseline: 1.1242x; 1.1242x over previous
//
#include <hip/hip_runtime.h>

// MultiHeadAttention: B=4, T=2048, C=1024, H=16, HD=64
// prep WtQ/K/V -> fused QKV GEMM (round-6 2-phase dbuf, best measured) ->
// flash attention (8-wave blocks + T5 setprio, XCD-local bh) -> prep WtO ->
// out GEMM (round-6 2-phase dbuf).
// This round: attn restructured to 512 blocks x 8 waves (staging amortized
// over 2x waves: 2 gld_lds/wave/chunk instead of 4; block-loop total halves);
// s_setprio(1) around attn MFMA clusters. GEMMs byte-identical to round 6.
// Workspace (64 MiB): R0 Kp | R1 Qp->WtO | R2 Vc | R3 WtQ/K/V -> Y

#define BATCH 4
#define T_SEQ 2048
#define C_DIM 1024
#define NH 16
#define HD 64

typedef _Float16 f16;
typedef __attribute__((ext_vector_type(4))) _Float16 half4;
typedef __attribute__((ext_vector_type(8))) _Float16 half8;
typedef __attribute__((ext_vector_type(4))) float f32x4;

__device__ inline void gld_lds16(const f16* g, f16* l) {
    __builtin_amdgcn_global_load_lds(
        (const __attribute__((address_space(1))) void*)g,
        (__attribute__((address_space(3))) void*)l, 16, 0, 0);
}

// ---------------------------------------------------------------------------
// prep: dst[n][k] f16 = (f32 src[k][n]) transposed. 64x64 tile per block.
// ---------------------------------------------------------------------------
__device__ inline void prep_tile(const float* __restrict__ src, f16* __restrict__ dst)
{
    __shared__ __align__(16) f16 Tl[64][72];
    const int tid = threadIdx.x;
    const int k0 = blockIdx.x * 64, n0 = blockIdx.y * 64;
#pragma unroll
    for (int p = 0; p < 4; ++p) {
        const int kr = p * 16 + (tid >> 4);
        const int nc = (tid & 15) * 4;
        float4 v = *(const float4*)(src + (size_t)(k0 + kr) * C_DIM + n0 + nc);
        Tl[nc + 0][kr] = (f16)v.x;
        Tl[nc + 1][kr] = (f16)v.y;
        Tl[nc + 2][kr] = (f16)v.z;
        Tl[nc + 3][kr] = (f16)v.w;
    }
    __syncthreads();
#pragma unroll
    for (int p = 0; p < 2; ++p) {
        const int nr = p * 32 + (tid >> 3);
        const int kc = (tid & 7) * 8;
        *(half8*)(dst + (size_t)(n0 + nr) * C_DIM + k0 + kc) = *(const half8*)&Tl[nr][kc];
    }
}

__global__ __launch_bounds__(256) void prep_weights(const float* __restrict__ src,
                                                    f16* __restrict__ dst)
{
    prep_tile(src, dst);
}

__global__ __launch_bounds__(256) void prep_weights3(const float* __restrict__ W0,
                                                     const float* __restrict__ W1,
                                                     const float* __restrict__ W2,
                                                     f16* __restrict__ D0,
                                                     f16* __restrict__ D1,
                                                     f16* __restrict__ D2)
{
    const int z = blockIdx.z;
    const float* src = (z == 0) ? W0 : (z == 1) ? W1 : W2;
    f16* dst = (z == 0) ? D0 : (z == 1) ? D1 : D2;
    prep_tile(src, dst);
}

// ---------------------------------------------------------------------------
// Fused QKV projection GEMM: 3 x (8192x1024 = X @ W + b). Grid (192,8).
// Round-6 form exactly: 128x128 tile, 4 waves, 4x4 MFMA, BK=32, 2-phase dbuf
// (prefetch A->regs + B gld_lds into buf^1, MFMA on buf, cvt+ds_write A,
// one __syncthreads per K-step). A stride-40 (conflict-free); B XOR-swizzled.
// g=0: f16 head-major Q, scaled 0.125*log2e.
// g=1: f16 head-major K, d-granule rotation ((d>>3)+t)&7.
// g=2: f16 chunked V [head][t>>6][d][key], key-granule rotation ((t>>3)+d)&7.
// ---------------------------------------------------------------------------
__global__ __launch_bounds__(256) void qkv_gemm(const float* __restrict__ Xq,
                                                const float* __restrict__ Xk,
                                                const float* __restrict__ Xv,
                                                const f16* __restrict__ Wt3,
                                                const float* __restrict__ bqp,
                                                const float* __restrict__ bkp,
                                                const float* __restrict__ bvp,
                                                f16* __restrict__ Qp,
                                                f16* __restrict__ Kp,
                                                f16* __restrict__ Vc)
{
    __shared__ __align__(16) f16 As[2][128 * 40];
    __shared__ __align__(16) f16 Bs[2][128 * 32];

    const int g = blockIdx.x >> 6;
    const float* __restrict__ Xf   = (g == 0) ? Xq : (g == 1) ? Xk : Xv;
    const float* __restrict__ bias = (g == 0) ? bqp : (g == 1) ? bkp : bvp;
    const f16* __restrict__ Wt     = Wt3 + (size_t)g * C_DIM * C_DIM;
    f16* __restrict__ outH         = (g == 0) ? Qp : (g == 1) ? Kp : Vc;

    const int tid  = threadIdx.x;
    const int m0   = (blockIdx.x & 63) * 128;
    const int n0   = blockIdx.y * 128;
    const int lane = tid & 63;
    const int wv   = tid >> 6;
    const int wm   = (wv >> 1) * 64;
    const int wn   = (wv & 1) * 64;
    const int l15  = lane & 15;
    const int quad = lane >> 4;
    const int xg   = (quad ^ ((l15 >> 1) & 3)) << 3;          // read-side swizzled col
    const int cSwz = ((lane & 3) ^ ((lane >> 3) & 3)) << 3;   // write-side source col
    const int ar   = tid / 8;
    const int ac4  = (tid & 7) * 4;
    const int brow = (wv * 2) * 16 + (lane >> 2);

    f32x4 acc[4][4];
#pragma unroll
    for (int i = 0; i < 4; i++)
#pragma unroll
        for (int j = 0; j < 4; j++) acc[i][j] = (f32x4){0.f, 0.f, 0.f, 0.f};

    // ---- prologue: stage tile 0 into buf 0 ----
#pragma unroll
    for (int i = 0; i < 4; i++) {
        float4 v = *(const float4*)(Xf + (size_t)(m0 + ar + i * 32) * C_DIM + ac4);
        half4 h;
        h[0] = (f16)v.x; h[1] = (f16)v.y; h[2] = (f16)v.z; h[3] = (f16)v.w;
        *(half4*)&As[0][(ar + i * 32) * 40 + ac4] = h;
    }
#pragma unroll
    for (int i = 0; i < 2; ++i)
        gld_lds16(Wt + (size_t)(n0 + brow + i * 16) * C_DIM + cSwz, &Bs[0][(wv * 2 + i) * 512]);
    __syncthreads();

    for (int kt = 0; kt < 32; ++kt) {
        const int cur = kt & 1, nxt = cur ^ 1;
        const int kk  = (kt + 1) * 32;

        // ---- prefetch tile kt+1: A -> regs, B -> Bs[nxt] via gld_lds ----
        float4 av[4];
        if (kt < 31) {
#pragma unroll
            for (int i = 0; i < 4; i++)
                av[i] = *(const float4*)(Xf + (size_t)(m0 + ar + i * 32) * C_DIM + kk + ac4);
#pragma unroll
            for (int i = 0; i < 2; ++i)
                gld_lds16(Wt + (size_t)(n0 + brow + i * 16) * C_DIM + kk + cSwz,
                          &Bs[nxt][(wv * 2 + i) * 512]);
        }

        // ---- compute on buf cur ----
        half8 af[4], bf[4];
#pragma unroll
        for (int t = 0; t < 4; t++) af[t] = *(const half8*)&As[cur][(wm + t * 16 + l15) * 40 + quad * 8];
#pragma unroll
        for (int t = 0; t < 4; t++) bf[t] = *(const half8*)&Bs[cur][(wn + t * 16 + l15) * 32 + xg];
#pragma unroll
        for (int tm = 0; tm < 4; tm++)
#pragma unroll
            for (int tn = 0; tn < 4; tn++)
                acc[tm][tn] = __builtin_amdgcn_mfma_f32_16x16x32_f16(af[tm], bf[tn], acc[tm][tn], 0, 0, 0);

        // ---- write prefetched A into As[nxt] ----
        if (kt < 31) {
#pragma unroll
            for (int i = 0; i < 4; i++) {
                half4 h;
                h[0] = (f16)av[i].x; h[1] = (f16)av[i].y;
                h[2] = (f16)av[i].z; h[3] = (f16)av[i].w;
                *(half4*)&As[nxt][(ar + i * 32) * 40 + ac4] = h;
            }
        }
        __syncthreads();   // drains gld_lds + ds_writes; buf nxt ready
    }

    // ---- epilogue (g is wave-uniform) ----
#pragma unroll
    for (int tm = 0; tm < 4; tm++) {
        const int gmb = m0 + wm + tm * 16 + quad * 4;
#pragma unroll
        for (int tn = 0; tn < 4; tn++) {
            const int gn = n0 + wn + tn * 16 + l15;
            const float bv = bias[gn];
            const int h = gn >> 6;
            const int d = gn & 63;
#pragma unroll
            for (int r = 0; r < 4; r++) {
                const int row = gmb + r;
                const float val = acc[tm][tn][r] + bv;
                const int b = row >> 11;
                const int t = row & (T_SEQ - 1);
                const size_t hb = ((size_t)(b * NH + h)) * T_SEQ * HD;
                if (g == 0) {
                    outH[hb + (size_t)t * HD + d] = (f16)(val * 0.18033688f); // 0.125*log2e
                } else if (g == 1) {
                    outH[hb + (size_t)t * HD + ((((d >> 3) + t) & 7) << 3) + (d & 7)] = (f16)val;
                } else {
                    outH[hb + (size_t)(t >> 6) * 4096 + d * 64 +
                         ((((t >> 3) + d) & 7) << 3) + (t & 7)] = (f16)val;
                }
            }
        }
    }
}

// ---------------------------------------------------------------------------
// Out GEMM: out(8192x1024) f32 = Y(f16) @ WtO + bo. Round-6 form: grid (64,8),
// BK=32, 2-phase dbuf, both operands gld_lds, XOR swizzle.
// ---------------------------------------------------------------------------
__global__ __launch_bounds__(256) void gemm_out(const f16* __restrict__ Xh,
                                                const f16* __restrict__ Wt,
                                                const float* __restrict__ bias,
                                                float* __restrict__ outF)
{
    __shared__ __align__(16) f16 As[2][128 * 32];
    __shared__ __align__(16) f16 Bs[2][128 * 32];

    const int tid  = threadIdx.x;
    const int m0   = blockIdx.x * 128;
    const int n0   = blockIdx.y * 128;
    const int lane = tid & 63;
    const int wv   = tid >> 6;
    const int wm   = (wv >> 1) * 64;
    const int wn   = (wv & 1) * 64;
    const int l15  = lane & 15;
    const int quad = lane >> 4;
    const int xg   = (quad ^ ((l15 >> 1) & 3)) << 3;
    const int cSwz = ((lane & 3) ^ ((lane >> 3) & 3)) << 3;
    const int brow = (wv * 2) * 16 + (lane >> 2);

    f32x4 acc[4][4];
#pragma unroll
    for (int i = 0; i < 4; i++)
#pragma unroll
        for (int j = 0; j < 4; j++) acc[i][j] = (f32x4){0.f, 0.f, 0.f, 0.f};

#pragma unroll
    for (int i = 0; i < 2; ++i) {
        gld_lds16(Xh + (size_t)(m0 + brow + i * 16) * C_DIM + cSwz, &As[0][(wv * 2 + i) * 512]);
        gld_lds16(Wt + (size_t)(n0 + brow + i * 16) * C_DIM + cSwz, &Bs[0][(wv * 2 + i) * 512]);
    }
    __syncthreads();

    for (int kt = 0; kt < 32; ++kt) {
        const int cur = kt & 1, nxt = cur ^ 1;
        const int kk  = (kt + 1) * 32;

        if (kt < 31) {
#pragma unroll
            for (int i = 0; i < 2; ++i) {
                gld_lds16(Xh + (size_t)(m0 + brow + i * 16) * C_DIM + kk + cSwz, &As[nxt][(wv * 2 + i) * 512]);
                gld_lds16(Wt + (size_t)(n0 + brow + i * 16) * C_DIM + kk + cSwz, &Bs[nxt][(wv * 2 + i) * 512]);
            }
        }

        half8 af[4], bf[4];
#pragma unroll
        for (int t = 0; t < 4; t++) af[t] = *(const half8*)&As[cur][(wm + t * 16 + l15) * 32 + xg];
#pragma unroll
        for (int t = 0; t < 4; t++) bf[t] = *(const half8*)&Bs[cur][(wn + t * 16 + l15) * 32 + xg];
#pragma unroll
        for (int tm = 0; tm < 4; tm++)
#pragma unroll
            for (int tn = 0; tn < 4; tn++)
                acc[tm][tn] = __builtin_amdgcn_mfma_f32_16x16x32_f16(af[tm], bf[tn], acc[tm][tn], 0, 0, 0);
        __syncthreads();
    }

#pragma unroll
    for (int tm = 0; tm < 4; tm++) {
        const int gmb = m0 + wm + tm * 16 + quad * 4;
#pragma unroll
        for (int tn = 0; tn < 4; tn++) {
            const int gn = n0 + wn + tn * 16 + l15;
            const float bv = bias[gn];
#pragma unroll
            for (int r = 0; r < 4; r++)
                outF[(size_t)(gmb + r) * C_DIM + gn] = acc[tm][tn][r] + bv;
        }
    }
}

// ---------------------------------------------------------------------------
// Flash attention — 8-wave blocks: grid 512 = 64 heads x 8, 512 thr.
// Wave u = ub*8+wv owns q-tiles u (rows 16u..) and 127-u (rows 2032-16u..).
// Staging of each 8KB K/V chunk amortized over 8 waves (1 gld_lds per wave
// per buffer). All per-wave math identical to the 4-wave version.
// T5: s_setprio(1) around MFMA clusters. XCD-local bh (blockIdx & 63).
// ---------------------------------------------------------------------------
__global__ __launch_bounds__(512) void attn_kernel(const f16* __restrict__ Qp,
                                                   const f16* __restrict__ Kp,
                                                   const f16* __restrict__ Vc,
                                                   f16* __restrict__ Y)
{
    __shared__ __align__(16) f16 Ks[2][4096];
    __shared__ __align__(16) f16 Vs[2][4096];

    const int tid  = threadIdx.x;
    const int lane = tid & 63;
    const int wv   = tid >> 6;          // 0..7
    const int l15  = lane & 15;
    const int quad = lane >> 4;
    const int bh   = blockIdx.x & 63;   // same-bh blocks -> same XCD (512 grid)
    const int ub   = blockIdx.x >> 6;   // 0..7
    const int u    = (ub << 3) | wv;    // 0..63
    int qT[2];
    qT[0] = 16 * u;
    qT[1] = 2032 - 16 * u;

    const f16* Qh = Qp + (size_t)bh * T_SEQ * HD;
    const f16* Kh = Kp + (size_t)bh * T_SEQ * HD;
    const f16* Vh = Vc + (size_t)bh * T_SEQ * HD;

    // Q fragments (B-operand of S^T): Q[q=l15][d=kh*32+quad*8+j]
    half8 aq[2][2];
#pragma unroll
    for (int m = 0; m < 2; m++)
#pragma unroll
        for (int kh = 0; kh < 2; kh++)
            aq[m][kh] = *(const half8*)(Qh + (size_t)(qT[m] + l15) * HD + kh * 32 + quad * 8);

    f32x4 o[2][4];
#pragma unroll
    for (int m = 0; m < 2; m++)
#pragma unroll
        for (int dt = 0; dt < 4; dt++) o[m][dt] = (f32x4){0.f, 0.f, 0.f, 0.f};
    float lsum[2] = {0.f, 0.f};

    const int nC0   = (16 * u + 79) >> 6;      // chunks where m=0 tile is active
    const int nC1   = (2111 - 16 * u) >> 6;    // chunks where m=1 tile is active
    const int nCblk = (2111 - 128 * ub) >> 6;  // block loop = max over waves (wv=0)

    // identity-copy staging: chunk kc is 8KB contiguous in both K and V;
    // 8 waves x 512 f16 each = 4096 f16 per buffer, ONE gld_lds per wave/buf
    auto stage = [&](int buf, int kc) {
        const f16* kg = Kh + (size_t)kc * 4096 + wv * 512;
        const f16* vg = Vh + (size_t)kc * 4096 + wv * 512;
        gld_lds16(kg + lane * 8, &Ks[buf][wv * 512]);
        gld_lds16(vg + lane * 8, &Vs[buf][wv * 512]);
    };

    stage(0, 0);
    __syncthreads();

    for (int kc = 0; kc < nCblk; ++kc) {
        const int cur = kc & 1;
        if (kc + 1 < nCblk) stage(cur ^ 1, kc + 1);   // prefetch in flight

        if (kc < nC1) {   // wave-uniform
            const int k0 = kc * 64;
            const int mStart = (kc < nC0) ? 0 : 1;

            // ---- S^T = K Q^T (K rows from LDS, rotation undone at read) ----
            f32x4 st[2][4];
            __builtin_amdgcn_s_setprio(1);
#pragma unroll
            for (int nt = 0; nt < 4; ++nt) {
                const f16* kr = &Ks[cur][(nt * 16 + l15) * 64];
                half8 bk0 = *(const half8*)(kr + (((quad + l15) & 7) << 3));
                half8 bk1 = *(const half8*)(kr + (((4 + quad + l15) & 7) << 3));
                {
                    f32x4 z = (f32x4){0.f, 0.f, 0.f, 0.f};
                    z = __builtin_amdgcn_mfma_f32_16x16x32_f16(bk0, aq[1][0], z, 0, 0, 0);
                    z = __builtin_amdgcn_mfma_f32_16x16x32_f16(bk1, aq[1][1], z, 0, 0, 0);
                    st[1][nt] = z;
                }
                if (mStart == 0) {
                    f32x4 z = (f32x4){0.f, 0.f, 0.f, 0.f};
                    z = __builtin_amdgcn_mfma_f32_16x16x32_f16(bk0, aq[0][0], z, 0, 0, 0);
                    z = __builtin_amdgcn_mfma_f32_16x16x32_f16(bk1, aq[0][1], z, 0, 0, 0);
                    st[0][nt] = z;
                }
            }
            __builtin_amdgcn_s_setprio(0);

            // ---- P^T = exp2(S^T) (Q pre-scaled by log2e), causal mask ----
            half4 pf[2][4];
#pragma unroll
            for (int m = 0; m < 2; ++m) {
                if (m < mStart) continue;
                const bool needMask = (k0 + 63 > qT[m]);
                const int q = qT[m] + l15;
#pragma unroll
                for (int nt = 0; nt < 4; ++nt) {
#pragma unroll
                    for (int r = 0; r < 4; ++r) {
                        const int key = k0 + nt * 16 + quad * 4 + r;
                        float p = __builtin_exp2f(st[m][nt][r]);
                        if (needMask && key > q) p = 0.f;
                        lsum[m] += p;
                        pf[m][nt][r] = (f16)p;
                    }
                }
            }

            // ---- O += P V (V rows from LDS, rotation undone at read) ----
            __builtin_amdgcn_s_setprio(1);
#pragma unroll
            for (int nt = 0; nt < 4; ++nt) {
                const int c0 = nt * 2 + (quad >> 1);
#pragma unroll
                for (int dt = 0; dt < 4; ++dt) {
                    const int d = dt * 16 + l15;
                    half4 bv = *(const half4*)(&Vs[cur][d * 64 + (((c0 + d) & 7) << 3) + ((quad & 1) << 2)]);
                    o[1][dt] = __builtin_amdgcn_mfma_f32_16x16x16f16(pf[1][nt], bv, o[1][dt], 0, 0, 0);
                    if (mStart == 0)
                        o[0][dt] = __builtin_amdgcn_mfma_f32_16x16x16f16(pf[0][nt], bv, o[0][dt], 0, 0, 0);
                }
            }
            __builtin_amdgcn_s_setprio(0);
        }
        __syncthreads();   // reads of cur done; prefetch into cur^1 landed
    }

    // ---- reduce l across quads, broadcast to rows, write Y ----
    const int b = bh >> 4;
    const int h = bh & 15;
#pragma unroll
    for (int m = 0; m < 2; m++) {
        float l = lsum[m];
        l += __shfl_xor(l, 16);
        l += __shfl_xor(l, 32);
#pragma unroll
        for (int r = 0; r < 4; r++) {
            const float lr  = __shfl(l, quad * 4 + r);
            const float inv = 1.0f / lr;
            const int qr = qT[m] + quad * 4 + r;
#pragma unroll
            for (int dt = 0; dt < 4; dt++)
                Y[((size_t)(b * T_SEQ + qr)) * C_DIM + h * HD + dt * 16 + l15] = (f16)(o[m][dt][r] * inv);
        }
    }
}

// ---------------------------------------------------------------------------
extern "C" void kernel_launch(void* const* d_in, const int* in_sizes, int n_in,
                              void* d_out, int out_size, void* d_ws, size_t ws_size,
                              hipStream_t stream)
{
    const float* k  = (const float*)d_in[0];
    const float* q  = (const float*)d_in[1];
    const float* v  = (const float*)d_in[2];
    const float* Wk = (const float*)d_in[4];
    const float* bk = (const float*)d_in[5];
    const float* Wq = (const float*)d_in[6];
    const float* bq = (const float*)d_in[7];
    const float* Wv = (const float*)d_in[8];
    const float* bv = (const float*)d_in[9];
    const float* Wo = (const float*)d_in[10];
    const float* bo = (const float*)d_in[11];
    float* out = (float*)d_out;

    const size_t E  = (size_t)BATCH * T_SEQ * C_DIM;
    const size_t WE = (size_t)C_DIM * C_DIM;

    f16* R0 = (f16*)d_ws;
    f16* R1 = R0 + E;
    f16* R2 = R1 + E;
    f16* R3 = R2 + E;

    f16* Kp  = R0;
    f16* Qp  = R1;
    f16* Vc  = R2;
    f16* Y   = R3;
    f16* WtQ = R3;
    f16* WtK = R3 + WE;
    f16* WtV = R3 + 2 * WE;
    f16* WtO = R1;

    dim3 blk(256);
    prep_weights3<<<dim3(16, 16, 3), blk, 0, stream>>>(Wq, Wk, Wv, WtQ, WtK, WtV);
    qkv_gemm<<<dim3(192, 8), blk, 0, stream>>>(q, k, v, WtQ, bq, bk, bv, Qp, Kp, Vc);
    attn_kernel<<<dim3(512), dim3(512), 0, stream>>>(Qp, Kp, Vc, Y);
    prep_weights<<<dim3(16, 16), blk, 0, stream>>>(Wo, WtO);
    gemm_out<<<dim3(64, 8), blk, 0, stream>>>(Y, WtO, bo, out);
}